// Round 13
// baseline (91.178 us; speedup 1.0000x reference)
//
#include <hip/hip_runtime.h>
#include <hip/hip_fp16.h>

// PhotometricLoss: total = 0.8*L1 + 0.2*DSSIM; fused separable 11x11 Gaussian
// SSIM, SAME zero padding. Inputs BHWC fp32 (B=4,H=1080,W=1920,C=3).
// R13: MFMA banded-GEMM conv, instruction-diet pass:
//  - dead-MFMA removal (wf[0]/wf[3] bands are all-zero): 30 -> 20 MFMA/wave
//  - interleaved (x,y) pair staging: 1 ds_write_b64/item, 1 ds_read_b128
//    feeds both planes in the h-pass
//  - sV exchange as float4 [px][4]: 4 b128 reads/thread, immediate-offset
//    b32 writes, no swizzle math (2-way conflicts are free)
// One wave per moment plane {x, y, x2+y2, xy}; register-chained h->v pass.

typedef __fp16 hf4 __attribute__((ext_vector_type(4)));
typedef float f32x4 __attribute__((ext_vector_type(4)));

#define TW 32
#define TH 32
#define IH 42         // staged real rows (rows 42..47 zero)
#define NPAIR 21      // data col-pairs per row
#define SPAIR 26      // staged row stride in uint2 (208 B = 13x16, b128-aligned)
#define NSLOT 512
#define HH 1080
#define WW 1920
#define GX 180
#define GY 34

// Gaussian(sigma=1.5, 11 taps), normalized; matches fp32 reference within ~2e-7
static constexpr float G[11] = {
    0.00102838f, 0.00759876f, 0.03600077f, 0.10936069f, 0.21300554f,
    0.26601174f, 0.21300554f, 0.10936069f, 0.03600077f, 0.00759876f,
    0.00102838f};

// ---- constexpr f32 -> f16 bits (RNE); G values are all f16-normal
constexpr unsigned short f2h_cx(float f) {
    unsigned u = __builtin_bit_cast(unsigned, f);
    if ((u & 0x7fffffffu) == 0) return 0;
    int e = (int)((u >> 23) & 0xff) - 127 + 15;
    unsigned man = u & 0x7fffffu;
    unsigned m = man >> 13;
    unsigned rest = man & 0x1fffu;
    if (rest > 0x1000u || (rest == 0x1000u && (m & 1u))) {
        if (++m == 0x400u) { m = 0; ++e; }
    }
    return (unsigned short)((e << 10) | m);
}
constexpr float Gf(int d) { return (d >= 0 && d <= 10) ? G[d] : 0.0f; }
constexpr unsigned wpk(int d) {
    return (unsigned)f2h_cx(Gf(d)) | ((unsigned)f2h_cx(Gf(d + 1)) << 16);
}
// Band fragment tables, only the two NONZERO tile-deltas:
// idx 0 (dl=1): halves g[lk - lr + i]; idx 1 (dl=2): g[16 + lk - lr + i].
struct WTbl {
    unsigned long long v[2][64];
    constexpr WTbl() : v{} {
        for (int dl = 0; dl < 2; ++dl)
            for (int l = 0; l < 64; ++l) {
                int d0 = 16 * dl + ((l >> 4) << 2) - (l & 15);
                v[dl][l] = (unsigned long long)wpk(d0) |
                           ((unsigned long long)wpk(d0 + 2) << 32);
            }
    }
};
__device__ const WTbl WT{};

struct f4u { float x, y, z, w; } __attribute__((packed, aligned(4)));

__device__ __forceinline__ unsigned int pkrtz(float a, float b) {
    return __builtin_bit_cast(unsigned int, __builtin_amdgcn_cvt_pkrtz(a, b));
}
__device__ __forceinline__ hf4 pk4(const f32x4& d) {
    uint2 u = make_uint2(pkrtz(d[0], d[1]), pkrtz(d[2], d[3]));
    return __builtin_bit_cast(hf4, u);
}
__device__ __forceinline__ f32x4 mfma16(hf4 a, hf4 b, f32x4 c) {
#if defined(__HIP_DEVICE_COMPILE__)
    return __builtin_amdgcn_mfma_f32_16x16x16f16(a, b, c, 0, 0, 0);
#else
    (void)a; (void)b;
    return c;   // host pass: never executed, just needs to parse
#endif
}

__global__ __launch_bounds__(256, 8) void photo_main(
    const float* __restrict__ xin, const float* __restrict__ yin,
    double* __restrict__ accum, int B, int nwg)
{
    __shared__ __align__(16) unsigned char smem[16384];  // staging 9984B | sV 16KB
    __shared__ float red[8];
    uint2* sXY = (uint2*)smem;          // [48][SPAIR] {x-pair, y-pair}
    float* sVf = (float*)smem;          // [1024][4] after h-pass barrier

    // ---- bijective XCD swizzle (nwg % 8 == 0), channel fastest in x
    int orig = blockIdx.x + GX * (blockIdx.y + GY * blockIdx.z);
    int nid = ((nwg & 7) == 0) ? ((orig & 7) * (nwg >> 3) + (orig >> 3)) : orig;
    int bx   = nid % GX;
    int rest = nid / GX;
    int by   = rest % GY;
    int b    = rest / GY;
    int c    = bx % 3;
    int tx   = bx / 3;
    const int row0 = by * TH, col0 = tx * TW;
    const int tid  = threadIdx.x;
    const int lane = tid & 63;
    const int wid  = tid >> 6;          // wave id == moment plane q
    const int imgbase = b * (HH * WW * 3) + c;

    // ---- zero-fill staging region (624 uint4 = 9984 B: rows/pads must be 0)
    {
        uint4 z = make_uint4(0, 0, 0, 0);
        #pragma unroll
        for (int j = 0; j < 3; ++j) {
            int idx = tid + j * 256;
            if (idx < 624) ((uint4*)smem)[idx] = z;
        }
    }
    __syncthreads();

    // ---- Phase 1a: stage interleaved (x,y) f16 pairs; fold L1 over center
    float l1_sum = 0.f;
    const bool interior = (tx >= 1) && (tx <= 58) && (by >= 1) && (by <= 32);
    if (interior) {
        for (int i = tid; i < IH * NPAIR; i += 256) {
            int r  = i / NPAIR;
            int pc = i - r * NPAIR;
            int gr  = row0 - 5 + r;
            int gc0 = col0 - 5 + 2 * pc;
            int base = imgbase + (gr * WW + gc0) * 3;
            f4u vx = *(const f4u*)&xin[base];     // x0 = .x, x1 = .w (stride-3)
            f4u vy = *(const f4u*)&yin[base];
            float x0 = vx.x, x1 = vx.w, y0 = vy.x, y1 = vy.w;
            sXY[r * SPAIR + pc] = make_uint2(pkrtz(x0, x1), pkrtz(y0, y1));
            if (r >= 5 && r < 5 + TH) {
                if (pc >= 3 && pc <= 18) l1_sum += fabsf(x0 - y0);
                if (pc >= 2 && pc <= 17) l1_sum += fabsf(x1 - y1);
            }
        }
    } else {
        #pragma unroll 1
        for (int i = tid; i < IH * NPAIR; i += 256) {
            int r  = i / NPAIR;
            int pc = i - r * NPAIR;
            int gr  = row0 - 5 + r;
            int gc0 = col0 - 5 + 2 * pc;
            bool rin = (unsigned)gr < (unsigned)HH;
            bool c0  = rin && ((unsigned)gc0       < (unsigned)WW);
            bool c1  = rin && ((unsigned)(gc0 + 1) < (unsigned)WW);
            int base = imgbase + (gr * WW + gc0) * 3;
            float x0 = 0.f, x1 = 0.f, y0 = 0.f, y1 = 0.f;
            if (c0) { x0 = xin[base];     y0 = yin[base]; }
            if (c1) { x1 = xin[base + 3]; y1 = yin[base + 3]; }
            sXY[r * SPAIR + pc] = make_uint2(pkrtz(x0, x1), pkrtz(y0, y1));
            if (r >= 5 && r < 5 + TH) {
                if (c0 && pc >= 3 && pc <= 18) l1_sum += fabsf(x0 - y0);
                if (c1 && pc >= 2 && pc <= 17) l1_sum += fabsf(x1 - y1);
            }
        }
    }
    __syncthreads();

    // ---- W fragments: wfA (dl=1), wfB (dl=2) — the only nonzero bands
    hf4 wfA = __builtin_bit_cast(hf4, WT.v[0][lane]);
    hf4 wfB = __builtin_bit_cast(hf4, WT.v[1][lane]);

    // ---- h-pass: HC[48x32] = S x W2 per plane (wave = plane wid).
    // One b128 read delivers pairs P,P+1 of BOTH x and y:
    //   {x01[P], y01[P], x01[P+1], y01[P+1]} -> xv = (v.x,v.z), yv = (v.y,v.w)
    // D rows 16t+4*(l>>4)+reg == v-pass B-frag k -> register chain (bfr).
    const int lr = lane & 15;
    const int lk = (lane >> 4) << 2;
    hf4 bfr[3][2];
    #pragma unroll
    for (int t = 0; t < 3; ++t) {
        f32x4 d0 = {0.f, 0.f, 0.f, 0.f}, d1 = {0.f, 0.f, 0.f, 0.f};
        #pragma unroll
        for (int k2 = 0; k2 < 3; ++k2) {
            uint4 v = *(const uint4*)&sXY[(16 * t + lr) * SPAIR + 8 * k2 + (lk >> 1)];
            hf4 a;
            if (wid == 0) {
                a = __builtin_bit_cast(hf4, make_uint2(v.x, v.z));
            } else if (wid == 1) {
                a = __builtin_bit_cast(hf4, make_uint2(v.y, v.w));
            } else {
                hf4 xv = __builtin_bit_cast(hf4, make_uint2(v.x, v.z));
                hf4 yv = __builtin_bit_cast(hf4, make_uint2(v.y, v.w));
                a = (wid == 2) ? (hf4)(xv * xv + yv * yv) : (hf4)(xv * yv);
            }
            // band structure: k2=0 feeds n=0 only (wfA), k2=1 feeds both
            // (wfB for n=0, wfA for n=1), k2=2 feeds n=1 only (wfB).
            if (k2 == 0)      { d0 = mfma16(a, wfA, d0); }
            else if (k2 == 1) { d0 = mfma16(a, wfB, d0); d1 = mfma16(a, wfA, d1); }
            else              { d1 = mfma16(a, wfB, d1); }
        }
        bfr[t][0] = pk4(d0);
        bfr[t][1] = pk4(d1);
    }
    __syncthreads();    // staging reads complete; sV may now alias smem

    // ---- v-pass: OUT = Wv x HC, registers only (dead bands removed)
    f32x4 vacc[2][2];
    #pragma unroll
    for (int u = 0; u < 2; ++u)
        #pragma unroll
        for (int n = 0; n < 2; ++n)
            vacc[u][n] = (f32x4){0.f, 0.f, 0.f, 0.f};
    #pragma unroll
    for (int n = 0; n < 2; ++n) {
        vacc[0][n] = mfma16(wfA, bfr[0][n], vacc[0][n]);
        vacc[0][n] = mfma16(wfB, bfr[1][n], vacc[0][n]);
        vacc[1][n] = mfma16(wfA, bfr[1][n], vacc[1][n]);
        vacc[1][n] = mfma16(wfB, bfr[2][n], vacc[1][n]);
    }

    // ---- write plane results to sV [px][4]: one addr, immediate offsets
    {
        float* p = sVf + (lk * 32 + lr) * 4 + wid;   // R=lk+, col=lr+ base
        #pragma unroll
        for (int u = 0; u < 2; ++u)
            #pragma unroll
            for (int g2 = 0; g2 < 4; ++g2)
                #pragma unroll
                for (int n = 0; n < 2; ++n)
                    p[((16 * u + g2) * 32 + 16 * n) * 4] = vacc[u][n][g2];
    }
    __syncthreads();

    // ---- SSIM from the 4 planes, 4 px per thread, b128 reads
    const float C1c = 1e-4f, C2c = 9e-4f;
    float ssim_sum = 0.f;
    const float4* sV4 = (const float4*)smem;
    #pragma unroll
    for (int j = 0; j < 4; ++j) {
        int px = j * 256 + tid;
        if (row0 + (px >> 5) < HH) {
            float4 m = sV4[px];
            float mu1 = m.x, mu2 = m.y, s2s = m.z, s12 = m.w;
            float mu1s = mu1 * mu1, mu2s = mu2 * mu2, mu12 = mu1 * mu2;
            float ssum = s2s - mu1s - mu2s;      // sigma1^2 + sigma2^2
            float sxy  = s12 - mu12;
            float num = (2.f * mu12 + C1c) * (2.f * sxy + C2c);
            float den = (mu1s + mu2s + C1c) * (ssum + C2c);
            ssim_sum += num * __builtin_amdgcn_rcpf(den);
        }
    }

    // ---- Block reduction, then hashed double atomics
    #pragma unroll
    for (int off = 32; off > 0; off >>= 1) {
        ssim_sum += __shfl_down(ssim_sum, off);
        l1_sum   += __shfl_down(l1_sum, off);
    }
    if ((tid & 63) == 0) { red[wid] = ssim_sum; red[4 + wid] = l1_sum; }
    __syncthreads();
    if (tid == 0) {
        float s = red[0] + red[1] + red[2] + red[3];
        float l = red[4] + red[5] + red[6] + red[7];
        double* slot = accum + (size_t)(orig & (NSLOT - 1)) * 2;
        atomicAdd(&slot[0], (double)l);
        atomicAdd(&slot[1], (double)s);
    }
}

__global__ __launch_bounds__(NSLOT) void photo_final(
    const double* __restrict__ accum, float* __restrict__ out, double invN)
{
    __shared__ double sl[8], ss[8];
    int tid = threadIdx.x;
    double l = accum[tid * 2 + 0];
    double s = accum[tid * 2 + 1];
    #pragma unroll
    for (int off = 32; off > 0; off >>= 1) {
        l += __shfl_down(l, off);
        s += __shfl_down(s, off);
    }
    if ((tid & 63) == 0) { sl[tid >> 6] = l; ss[tid >> 6] = s; }
    __syncthreads();
    if (tid == 0) {
        double L = 0.0, S = 0.0;
        #pragma unroll
        for (int i = 0; i < NSLOT / 64; ++i) { L += sl[i]; S += ss[i]; }
        double l1    = L * invN;
        double ssim  = S * invN;
        double dssim = (1.0 - ssim) * 0.5;
        out[0] = (float)(0.8 * l1 + 0.2 * dssim);
        out[1] = (float)l1;
        out[2] = (float)dssim;
    }
}

extern "C" void kernel_launch(void* const* d_in, const int* in_sizes, int n_in,
                              void* d_out, int out_size, void* d_ws, size_t ws_size,
                              hipStream_t stream)
{
    const int H = 1080, W = 1920, C = 3;
    const float* x = (const float*)d_in[0];
    const float* y = (const float*)d_in[1];
    int B = in_sizes[0] / (H * W * C);

    double* accum = (double*)d_ws;
    (void)hipMemsetAsync(d_ws, 0, NSLOT * 2 * sizeof(double), stream);

    dim3 grid(GX, GY, B);
    int nwg = GX * GY * B;
    photo_main<<<grid, dim3(256), 0, stream>>>(x, y, accum, B, nwg);

    double invN = 1.0 / ((double)B * H * W * C);
    photo_final<<<1, NSLOT, 0, stream>>>(accum, (float*)d_out, invN);
}

// Round 14
// 60.458 us; speedup vs baseline: 1.5081x; 1.5081x over previous
//
#include <hip/hip_runtime.h>
#include <hip/hip_fp16.h>

// PhotometricLoss: total = 0.8*L1 + 0.2*DSSIM; fused separable 11x11 Gaussian
// SSIM, SAME zero padding. Inputs BHWC fp32 (B=4,H=1080,W=1920,C=3).
// R14: all-3-channels-per-block (kills the 3x L2->L1 line amplification of
// channel-per-block at stride-3) + quadrant-per-wave MFMA (wave = 16x16
// output quadrant, all 4 moment planes in-wave -> SSIM from registers, NO
// sV exchange). LDS = staging only (29.3KB) -> 5 blocks/CU.

typedef __fp16 hf4 __attribute__((ext_vector_type(4)));
typedef float f32x4 __attribute__((ext_vector_type(4)));

#define TW 32
#define TH 32
#define IH 42         // staged real rows (rows 42..47 zero)
#define NPAIR 21      // data col-pairs per row
#define SPAIR 26      // row stride in uint2 (208 B; rows 8 apart alias = 2-way, free)
#define CHS (48 * SPAIR)   // uint2 per channel plane (1248)
#define NSLOT 512
#define HH 1080
#define WW 1920
#define GX 60
#define GY 34

// Gaussian(sigma=1.5, 11 taps), normalized; matches fp32 reference within ~2e-7
static constexpr float G[11] = {
    0.00102838f, 0.00759876f, 0.03600077f, 0.10936069f, 0.21300554f,
    0.26601174f, 0.21300554f, 0.10936069f, 0.03600077f, 0.00759876f,
    0.00102838f};

// ---- constexpr f32 -> f16 bits (RNE); G values are all f16-normal
constexpr unsigned short f2h_cx(float f) {
    unsigned u = __builtin_bit_cast(unsigned, f);
    if ((u & 0x7fffffffu) == 0) return 0;
    int e = (int)((u >> 23) & 0xff) - 127 + 15;
    unsigned man = u & 0x7fffffu;
    unsigned m = man >> 13;
    unsigned rest = man & 0x1fffu;
    if (rest > 0x1000u || (rest == 0x1000u && (m & 1u))) {
        if (++m == 0x400u) { m = 0; ++e; }
    }
    return (unsigned short)((e << 10) | m);
}
constexpr float Gf(int d) { return (d >= 0 && d <= 10) ? G[d] : 0.0f; }
constexpr unsigned wpk(int d) {
    return (unsigned)f2h_cx(Gf(d)) | ((unsigned)f2h_cx(Gf(d + 1)) << 16);
}
// Band fragment tables (the only two nonzero tile-deltas):
// idx 0: halves g[lk - lr + i]; idx 1: g[16 + lk - lr + i].
struct WTbl {
    unsigned long long v[2][64];
    constexpr WTbl() : v{} {
        for (int dl = 0; dl < 2; ++dl)
            for (int l = 0; l < 64; ++l) {
                int d0 = 16 * dl + ((l >> 4) << 2) - (l & 15);
                v[dl][l] = (unsigned long long)wpk(d0) |
                           ((unsigned long long)wpk(d0 + 2) << 32);
            }
    }
};
__device__ const WTbl WT{};

struct f4u { float x, y, z, w; } __attribute__((packed, aligned(4)));

__device__ __forceinline__ unsigned int pkrtz(float a, float b) {
    return __builtin_bit_cast(unsigned int, __builtin_amdgcn_cvt_pkrtz(a, b));
}
__device__ __forceinline__ hf4 pk4(const f32x4& d) {
    uint2 u = make_uint2(pkrtz(d[0], d[1]), pkrtz(d[2], d[3]));
    return __builtin_bit_cast(hf4, u);
}
__device__ __forceinline__ f32x4 mfma16(hf4 a, hf4 b, f32x4 c) {
#if defined(__HIP_DEVICE_COMPILE__)
    return __builtin_amdgcn_mfma_f32_16x16x16f16(a, b, c, 0, 0, 0);
#else
    (void)a; (void)b;
    return c;   // host pass: never executed, just needs to parse
#endif
}

__global__ __launch_bounds__(256, 5) void photo_main(
    const float* __restrict__ xin, const float* __restrict__ yin,
    double* __restrict__ accum, int B, int nwg)
{
    __shared__ __align__(16) uint2 sXY[3 * CHS];   // 29952 B, channel-outer
    __shared__ float red[8];

    // ---- bijective XCD swizzle (nwg % 8 == 0)
    int orig = blockIdx.x + GX * (blockIdx.y + GY * blockIdx.z);
    int nid = ((nwg & 7) == 0) ? ((orig & 7) * (nwg >> 3) + (orig >> 3)) : orig;
    int tx   = nid % GX;
    int rest = nid / GX;
    int by   = rest % GY;
    int b    = rest / GY;
    const int row0 = by * TH, col0 = tx * TW;
    const int tid  = threadIdx.x;
    const int lane = tid & 63;
    const int wid  = tid >> 6;
    const int imgbase = b * (HH * WW * 3);

    // ---- zero-fill staging (rows 42..47, pairs 21..25 must be 0)
    {
        uint4 z = make_uint4(0, 0, 0, 0);
        uint4* z4 = (uint4*)sXY;
        #pragma unroll
        for (int j = 0; j < 8; ++j) {
            int idx = tid + j * 256;
            if (idx < 3 * CHS / 2) z4[idx] = z;
        }
    }
    __syncthreads();

    // ---- Phase 1a: stage all 3 channels as interleaved (x,y) f16 pairs;
    // fold L1 (all channels) over the central 32x32.
    float l1_sum = 0.f;
    const bool interior = (tx >= 1) && (tx <= 58) && (by >= 1) && (by <= 32);
    if (interior) {
        for (int i = tid; i < IH * NPAIR; i += 256) {
            int r  = i / NPAIR;
            int pc = i - r * NPAIR;
            int gr  = row0 - 5 + r;
            int gc0 = col0 - 5 + 2 * pc;
            int base = imgbase + (gr * WW + gc0) * 3;
            f4u vx0 = *(const f4u*)&xin[base];        // x0c0 x0c1 x0c2 x1c0
            f4u vx1 = *(const f4u*)&xin[base + 2];    // x0c2 x1c0 x1c1 x1c2
            f4u vy0 = *(const f4u*)&yin[base];
            f4u vy1 = *(const f4u*)&yin[base + 2];
            float x0[3] = {vx0.x, vx0.y, vx0.z};
            float x1[3] = {vx1.y, vx1.z, vx1.w};
            float y0[3] = {vy0.x, vy0.y, vy0.z};
            float y1[3] = {vy1.y, vy1.z, vy1.w};
            #pragma unroll
            for (int c = 0; c < 3; ++c)
                sXY[c * CHS + r * SPAIR + pc] =
                    make_uint2(pkrtz(x0[c], x1[c]), pkrtz(y0[c], y1[c]));
            if (r >= 5 && r < 5 + TH) {
                if (pc >= 3 && pc <= 18)
                    l1_sum += fabsf(x0[0] - y0[0]) + fabsf(x0[1] - y0[1]) +
                              fabsf(x0[2] - y0[2]);
                if (pc >= 2 && pc <= 17)
                    l1_sum += fabsf(x1[0] - y1[0]) + fabsf(x1[1] - y1[1]) +
                              fabsf(x1[2] - y1[2]);
            }
        }
    } else {
        #pragma unroll 1
        for (int i = tid; i < IH * NPAIR; i += 256) {
            int r  = i / NPAIR;
            int pc = i - r * NPAIR;
            int gr  = row0 - 5 + r;
            int gc0 = col0 - 5 + 2 * pc;
            bool rin = (unsigned)gr < (unsigned)HH;
            bool c0  = rin && ((unsigned)gc0       < (unsigned)WW);
            bool c1  = rin && ((unsigned)(gc0 + 1) < (unsigned)WW);
            int base = imgbase + (gr * WW + gc0) * 3;
            float x0[3] = {0.f, 0.f, 0.f}, x1[3] = {0.f, 0.f, 0.f};
            float y0[3] = {0.f, 0.f, 0.f}, y1[3] = {0.f, 0.f, 0.f};
            #pragma unroll
            for (int c = 0; c < 3; ++c) {
                if (c0) { x0[c] = xin[base + c];     y0[c] = yin[base + c]; }
                if (c1) { x1[c] = xin[base + 3 + c]; y1[c] = yin[base + 3 + c]; }
            }
            #pragma unroll
            for (int c = 0; c < 3; ++c)
                sXY[c * CHS + r * SPAIR + pc] =
                    make_uint2(pkrtz(x0[c], x1[c]), pkrtz(y0[c], y1[c]));
            if (r >= 5 && r < 5 + TH) {
                if (c0 && pc >= 3 && pc <= 18)
                    l1_sum += fabsf(x0[0] - y0[0]) + fabsf(x0[1] - y0[1]) +
                              fabsf(x0[2] - y0[2]);
                if (c1 && pc >= 2 && pc <= 17)
                    l1_sum += fabsf(x1[0] - y1[0]) + fabsf(x1[1] - y1[1]) +
                              fabsf(x1[2] - y1[2]);
            }
        }
    }
    __syncthreads();

    // ---- quadrant-per-wave conv: wave wid -> out quadrant (u,n), 16x16,
    // all 4 moment planes; register-chained h->v; SSIM from registers.
    const int lr = lane & 15;
    const int lk = (lane >> 4) << 2;
    const int u = wid >> 1, n = wid & 1;
    hf4 wfA = __builtin_bit_cast(hf4, WT.v[0][lane]);
    hf4 wfB = __builtin_bit_cast(hf4, WT.v[1][lane]);

    const float C1c = 1e-4f, C2c = 9e-4f;
    float ssim_sum = 0.f;
    #pragma unroll 1
    for (int ch = 0; ch < 3; ++ch) {
        const uint2* S = sXY + ch * CHS;
        // read the 4 staged b128 fragments (t = u+dt, k2 = n+dk)
        uint4 rd[2][2];
        #pragma unroll
        for (int dt = 0; dt < 2; ++dt)
            #pragma unroll
            for (int dk = 0; dk < 2; ++dk)
                rd[dt][dk] = *(const uint4*)
                    &S[(16 * (u + dt) + lr) * SPAIR + 8 * (n + dk) + (lk >> 1)];
        // h-pass: HC tiles t=u,u+1 for col-block n, 4 planes
        hf4 bfr[4][2];
        #pragma unroll
        for (int dt = 0; dt < 2; ++dt) {
            f32x4 d[4];
            #pragma unroll
            for (int p = 0; p < 4; ++p) d[p] = (f32x4){0.f, 0.f, 0.f, 0.f};
            #pragma unroll
            for (int dk = 0; dk < 2; ++dk) {
                uint4 v = rd[dt][dk];
                hf4 xv = __builtin_bit_cast(hf4, make_uint2(v.x, v.z));
                hf4 yv = __builtin_bit_cast(hf4, make_uint2(v.y, v.w));
                hf4 zv = xv * xv + yv * yv;
                hf4 wv = xv * yv;
                hf4 wB = dk ? wfB : wfA;
                d[0] = mfma16(xv, wB, d[0]);
                d[1] = mfma16(yv, wB, d[1]);
                d[2] = mfma16(zv, wB, d[2]);
                d[3] = mfma16(wv, wB, d[3]);
            }
            #pragma unroll
            for (int p = 0; p < 4; ++p) bfr[p][dt] = pk4(d[p]);
        }
        // v-pass: OUT quadrant = Wv x HC
        f32x4 vacc[4];
        #pragma unroll
        for (int p = 0; p < 4; ++p) {
            vacc[p] = (f32x4){0.f, 0.f, 0.f, 0.f};
            vacc[p] = mfma16(wfA, bfr[p][0], vacc[p]);
            vacc[p] = mfma16(wfB, bfr[p][1], vacc[p]);
        }
        // SSIM directly from registers
        #pragma unroll
        for (int g2 = 0; g2 < 4; ++g2) {
            int gr = row0 + 16 * u + lk + g2;
            if (gr < HH) {
                float mu1 = vacc[0][g2], mu2 = vacc[1][g2];
                float s2s = vacc[2][g2], s12 = vacc[3][g2];
                float mu1s = mu1 * mu1, mu2s = mu2 * mu2, mu12 = mu1 * mu2;
                float ssum = s2s - mu1s - mu2s;
                float sxy  = s12 - mu12;
                float num = (2.f * mu12 + C1c) * (2.f * sxy + C2c);
                float den = (mu1s + mu2s + C1c) * (ssum + C2c);
                ssim_sum += num * __builtin_amdgcn_rcpf(den);
            }
        }
    }

    // ---- Block reduction, then hashed double atomics
    #pragma unroll
    for (int off = 32; off > 0; off >>= 1) {
        ssim_sum += __shfl_down(ssim_sum, off);
        l1_sum   += __shfl_down(l1_sum, off);
    }
    if ((tid & 63) == 0) { red[wid] = ssim_sum; red[4 + wid] = l1_sum; }
    __syncthreads();
    if (tid == 0) {
        float s = red[0] + red[1] + red[2] + red[3];
        float l = red[4] + red[5] + red[6] + red[7];
        double* slot = accum + (size_t)(orig & (NSLOT - 1)) * 2;
        atomicAdd(&slot[0], (double)l);
        atomicAdd(&slot[1], (double)s);
    }
}

__global__ __launch_bounds__(NSLOT) void photo_final(
    const double* __restrict__ accum, float* __restrict__ out, double invN)
{
    __shared__ double sl[8], ss[8];
    int tid = threadIdx.x;
    double l = accum[tid * 2 + 0];
    double s = accum[tid * 2 + 1];
    #pragma unroll
    for (int off = 32; off > 0; off >>= 1) {
        l += __shfl_down(l, off);
        s += __shfl_down(s, off);
    }
    if ((tid & 63) == 0) { sl[tid >> 6] = l; ss[tid >> 6] = s; }
    __syncthreads();
    if (tid == 0) {
        double L = 0.0, S = 0.0;
        #pragma unroll
        for (int i = 0; i < NSLOT / 64; ++i) { L += sl[i]; S += ss[i]; }
        double l1    = L * invN;
        double ssim  = S * invN;
        double dssim = (1.0 - ssim) * 0.5;
        out[0] = (float)(0.8 * l1 + 0.2 * dssim);
        out[1] = (float)l1;
        out[2] = (float)dssim;
    }
}

extern "C" void kernel_launch(void* const* d_in, const int* in_sizes, int n_in,
                              void* d_out, int out_size, void* d_ws, size_t ws_size,
                              hipStream_t stream)
{
    const int H = 1080, W = 1920, C = 3;
    const float* x = (const float*)d_in[0];
    const float* y = (const float*)d_in[1];
    int B = in_sizes[0] / (H * W * C);

    double* accum = (double*)d_ws;
    (void)hipMemsetAsync(d_ws, 0, NSLOT * 2 * sizeof(double), stream);

    dim3 grid(GX, GY, B);
    int nwg = GX * GY * B;
    photo_main<<<grid, dim3(256), 0, stream>>>(x, y, accum, B, nwg);

    double invN = 1.0 / ((double)B * H * W * C);
    photo_final<<<1, NSLOT, 0, stream>>>(accum, (float*)d_out, invN);
}

// Round 15
// 58.636 us; speedup vs baseline: 1.5550x; 1.0311x over previous
//
#include <hip/hip_runtime.h>
#include <hip/hip_fp16.h>

// PhotometricLoss: total = 0.8*L1 + 0.2*DSSIM; fused separable 11x11 Gaussian
// SSIM, SAME zero padding. Inputs BHWC fp32 (B=4,H=1080,W=1920,C=3).
// R15 (= R14 + occupancy): stage only 42 real rows (pad rows 42..47 replaced
// by clamped reads -- their HC rows have structurally-zero v-pass weights,
// g-index >= 11, garbage bounded so no NaN*0) -> LDS 30.2 -> 26.2 KB ->
// 6 blocks/CU. Zero-fill shrunk to pair-cols 21..23 and merged into staging
// (one barrier deleted). SSIM full-quadrant fast path.

typedef __fp16 hf4 __attribute__((ext_vector_type(4)));
typedef float f32x4 __attribute__((ext_vector_type(4)));

#define TW 32
#define TH 32
#define IH 42         // staged real rows (no pad rows)
#define NPAIR 21      // data col-pairs per row
#define SPAIR 26      // row stride in uint2 (208 B: 2-way bank alias only)
#define CHS (IH * SPAIR)   // uint2 per channel plane (1092)
#define NSLOT 512
#define HH 1080
#define WW 1920
#define GX 60
#define GY 34

// Gaussian(sigma=1.5, 11 taps), normalized; matches fp32 reference within ~2e-7
static constexpr float G[11] = {
    0.00102838f, 0.00759876f, 0.03600077f, 0.10936069f, 0.21300554f,
    0.26601174f, 0.21300554f, 0.10936069f, 0.03600077f, 0.00759876f,
    0.00102838f};

// ---- constexpr f32 -> f16 bits (RNE); G values are all f16-normal
constexpr unsigned short f2h_cx(float f) {
    unsigned u = __builtin_bit_cast(unsigned, f);
    if ((u & 0x7fffffffu) == 0) return 0;
    int e = (int)((u >> 23) & 0xff) - 127 + 15;
    unsigned man = u & 0x7fffffu;
    unsigned m = man >> 13;
    unsigned rest = man & 0x1fffu;
    if (rest > 0x1000u || (rest == 0x1000u && (m & 1u))) {
        if (++m == 0x400u) { m = 0; ++e; }
    }
    return (unsigned short)((e << 10) | m);
}
constexpr float Gf(int d) { return (d >= 0 && d <= 10) ? G[d] : 0.0f; }
constexpr unsigned wpk(int d) {
    return (unsigned)f2h_cx(Gf(d)) | ((unsigned)f2h_cx(Gf(d + 1)) << 16);
}
// Band fragment tables (the only two nonzero tile-deltas):
// idx 0: halves g[lk - lr + i]; idx 1: g[16 + lk - lr + i].
struct WTbl {
    unsigned long long v[2][64];
    constexpr WTbl() : v{} {
        for (int dl = 0; dl < 2; ++dl)
            for (int l = 0; l < 64; ++l) {
                int d0 = 16 * dl + ((l >> 4) << 2) - (l & 15);
                v[dl][l] = (unsigned long long)wpk(d0) |
                           ((unsigned long long)wpk(d0 + 2) << 32);
            }
    }
};
__device__ const WTbl WT{};

struct f4u { float x, y, z, w; } __attribute__((packed, aligned(4)));

__device__ __forceinline__ unsigned int pkrtz(float a, float b) {
    return __builtin_bit_cast(unsigned int, __builtin_amdgcn_cvt_pkrtz(a, b));
}
__device__ __forceinline__ hf4 pk4(const f32x4& d) {
    uint2 u = make_uint2(pkrtz(d[0], d[1]), pkrtz(d[2], d[3]));
    return __builtin_bit_cast(hf4, u);
}
__device__ __forceinline__ f32x4 mfma16(hf4 a, hf4 b, f32x4 c) {
#if defined(__HIP_DEVICE_COMPILE__)
    return __builtin_amdgcn_mfma_f32_16x16x16f16(a, b, c, 0, 0, 0);
#else
    (void)a; (void)b;
    return c;   // host pass: never executed, just needs to parse
#endif
}

__global__ __launch_bounds__(256, 6) void photo_main(
    const float* __restrict__ xin, const float* __restrict__ yin,
    double* __restrict__ accum, int B, int nwg)
{
    __shared__ __align__(16) uint2 sXY[3 * CHS];   // 26208 B, channel-outer
    __shared__ float red[8];

    // ---- bijective XCD swizzle (nwg % 8 == 0)
    int orig = blockIdx.x + GX * (blockIdx.y + GY * blockIdx.z);
    int nid = ((nwg & 7) == 0) ? ((orig & 7) * (nwg >> 3) + (orig >> 3)) : orig;
    int tx   = nid % GX;
    int rest = nid / GX;
    int by   = rest % GY;
    int b    = rest / GY;
    const int row0 = by * TH, col0 = tx * TW;
    const int tid  = threadIdx.x;
    const int lane = tid & 63;
    const int wid  = tid >> 6;
    const int imgbase = b * (HH * WW * 3);

    // ---- zero-fill ONLY pair-cols 21..23 (read as h-pass K-padding);
    // cols 24,25 are never read, rows 42..47 no longer exist.
    // 378 items = 3 ch x 42 rows x 3 pairs; merged into staging phase.
    {
        int zi = tid;
        if (zi < 378) {
            int ch = zi / 126, rm = zi - ch * 126;
            int r = rm / 3, k = rm - r * 3;
            sXY[ch * CHS + r * SPAIR + 21 + k] = make_uint2(0u, 0u);
        }
        zi = tid + 256;
        if (zi < 378) {
            int ch = zi / 126, rm = zi - ch * 126;
            int r = rm / 3, k = rm - r * 3;
            sXY[ch * CHS + r * SPAIR + 21 + k] = make_uint2(0u, 0u);
        }
    }

    // ---- Phase 1a: stage all 3 channels as interleaved (x,y) f16 pairs;
    // fold L1 (all channels) over the central 32x32.
    float l1_sum = 0.f;
    const bool interior = (tx >= 1) && (tx <= 58) && (by >= 1) && (by <= 32);
    if (interior) {
        for (int i = tid; i < IH * NPAIR; i += 256) {
            int r  = i / NPAIR;
            int pc = i - r * NPAIR;
            int gr  = row0 - 5 + r;
            int gc0 = col0 - 5 + 2 * pc;
            int base = imgbase + (gr * WW + gc0) * 3;
            f4u vx0 = *(const f4u*)&xin[base];        // x0c0 x0c1 x0c2 x1c0
            f4u vx1 = *(const f4u*)&xin[base + 2];    // x0c2 x1c0 x1c1 x1c2
            f4u vy0 = *(const f4u*)&yin[base];
            f4u vy1 = *(const f4u*)&yin[base + 2];
            float x0[3] = {vx0.x, vx0.y, vx0.z};
            float x1[3] = {vx1.y, vx1.z, vx1.w};
            float y0[3] = {vy0.x, vy0.y, vy0.z};
            float y1[3] = {vy1.y, vy1.z, vy1.w};
            #pragma unroll
            for (int c = 0; c < 3; ++c)
                sXY[c * CHS + r * SPAIR + pc] =
                    make_uint2(pkrtz(x0[c], x1[c]), pkrtz(y0[c], y1[c]));
            if (r >= 5 && r < 5 + TH) {
                if (pc >= 3 && pc <= 18)
                    l1_sum += fabsf(x0[0] - y0[0]) + fabsf(x0[1] - y0[1]) +
                              fabsf(x0[2] - y0[2]);
                if (pc >= 2 && pc <= 17)
                    l1_sum += fabsf(x1[0] - y1[0]) + fabsf(x1[1] - y1[1]) +
                              fabsf(x1[2] - y1[2]);
            }
        }
    } else {
        #pragma unroll 1
        for (int i = tid; i < IH * NPAIR; i += 256) {
            int r  = i / NPAIR;
            int pc = i - r * NPAIR;
            int gr  = row0 - 5 + r;
            int gc0 = col0 - 5 + 2 * pc;
            bool rin = (unsigned)gr < (unsigned)HH;
            bool c0  = rin && ((unsigned)gc0       < (unsigned)WW);
            bool c1  = rin && ((unsigned)(gc0 + 1) < (unsigned)WW);
            int base = imgbase + (gr * WW + gc0) * 3;
            float x0[3] = {0.f, 0.f, 0.f}, x1[3] = {0.f, 0.f, 0.f};
            float y0[3] = {0.f, 0.f, 0.f}, y1[3] = {0.f, 0.f, 0.f};
            #pragma unroll
            for (int c = 0; c < 3; ++c) {
                if (c0) { x0[c] = xin[base + c];     y0[c] = yin[base + c]; }
                if (c1) { x1[c] = xin[base + 3 + c]; y1[c] = yin[base + 3 + c]; }
            }
            #pragma unroll
            for (int c = 0; c < 3; ++c)
                sXY[c * CHS + r * SPAIR + pc] =
                    make_uint2(pkrtz(x0[c], x1[c]), pkrtz(y0[c], y1[c]));
            if (r >= 5 && r < 5 + TH) {
                if (c0 && pc >= 3 && pc <= 18)
                    l1_sum += fabsf(x0[0] - y0[0]) + fabsf(x0[1] - y0[1]) +
                              fabsf(x0[2] - y0[2]);
                if (c1 && pc >= 2 && pc <= 17)
                    l1_sum += fabsf(x1[0] - y1[0]) + fabsf(x1[1] - y1[1]) +
                              fabsf(x1[2] - y1[2]);
            }
        }
    }
    __syncthreads();

    // ---- quadrant-per-wave conv: wave wid -> out quadrant (u,n), 16x16,
    // all 4 moment planes; register-chained h->v; SSIM from registers.
    const int lr = lane & 15;
    const int lk = (lane >> 4) << 2;
    const int u = wid >> 1, n = wid & 1;
    hf4 wfA = __builtin_bit_cast(hf4, WT.v[0][lane]);
    hf4 wfB = __builtin_bit_cast(hf4, WT.v[1][lane]);

    // clamped read rows: rows >= 42 (only t=2, lr >= 10) fold to row 41;
    // the garbage HC rows 42..47 carry structurally-zero v-pass weights.
    int rrow[2];
    #pragma unroll
    for (int dt = 0; dt < 2; ++dt)
        rrow[dt] = min(16 * (u + dt) + lr, IH - 1) * SPAIR;

    const float C1c = 1e-4f, C2c = 9e-4f;
    float ssim_sum = 0.f;
    const bool fullq = (row0 + 16 * u + 15) < HH;   // whole quadrant in-image
    #pragma unroll 1
    for (int ch = 0; ch < 3; ++ch) {
        const uint2* S = sXY + ch * CHS;
        // read the 4 staged b128 fragments (t = u+dt, k2 = n+dk)
        uint4 rd[2][2];
        #pragma unroll
        for (int dt = 0; dt < 2; ++dt)
            #pragma unroll
            for (int dk = 0; dk < 2; ++dk)
                rd[dt][dk] = *(const uint4*)
                    &S[rrow[dt] + 8 * (n + dk) + (lk >> 1)];
        // h-pass: HC tiles t=u,u+1 for col-block n, 4 planes
        hf4 bfr[4][2];
        #pragma unroll
        for (int dt = 0; dt < 2; ++dt) {
            f32x4 d[4];
            #pragma unroll
            for (int p = 0; p < 4; ++p) d[p] = (f32x4){0.f, 0.f, 0.f, 0.f};
            #pragma unroll
            for (int dk = 0; dk < 2; ++dk) {
                uint4 v = rd[dt][dk];
                hf4 xv = __builtin_bit_cast(hf4, make_uint2(v.x, v.z));
                hf4 yv = __builtin_bit_cast(hf4, make_uint2(v.y, v.w));
                hf4 zv = xv * xv + yv * yv;
                hf4 wv = xv * yv;
                hf4 wB = dk ? wfB : wfA;
                d[0] = mfma16(xv, wB, d[0]);
                d[1] = mfma16(yv, wB, d[1]);
                d[2] = mfma16(zv, wB, d[2]);
                d[3] = mfma16(wv, wB, d[3]);
            }
            #pragma unroll
            for (int p = 0; p < 4; ++p) bfr[p][dt] = pk4(d[p]);
        }
        // v-pass: OUT quadrant = Wv x HC
        f32x4 vacc[4];
        #pragma unroll
        for (int p = 0; p < 4; ++p) {
            vacc[p] = (f32x4){0.f, 0.f, 0.f, 0.f};
            vacc[p] = mfma16(wfA, bfr[p][0], vacc[p]);
            vacc[p] = mfma16(wfB, bfr[p][1], vacc[p]);
        }
        // SSIM directly from registers
        if (fullq) {
            #pragma unroll
            for (int g2 = 0; g2 < 4; ++g2) {
                float mu1 = vacc[0][g2], mu2 = vacc[1][g2];
                float s2s = vacc[2][g2], s12 = vacc[3][g2];
                float mu1s = mu1 * mu1, mu2s = mu2 * mu2, mu12 = mu1 * mu2;
                float ssum = s2s - mu1s - mu2s;
                float sxy  = s12 - mu12;
                float num = (2.f * mu12 + C1c) * (2.f * sxy + C2c);
                float den = (mu1s + mu2s + C1c) * (ssum + C2c);
                ssim_sum += num * __builtin_amdgcn_rcpf(den);
            }
        } else {
            #pragma unroll
            for (int g2 = 0; g2 < 4; ++g2) {
                int gr = row0 + 16 * u + lk + g2;
                if (gr < HH) {
                    float mu1 = vacc[0][g2], mu2 = vacc[1][g2];
                    float s2s = vacc[2][g2], s12 = vacc[3][g2];
                    float mu1s = mu1 * mu1, mu2s = mu2 * mu2, mu12 = mu1 * mu2;
                    float ssum = s2s - mu1s - mu2s;
                    float sxy  = s12 - mu12;
                    float num = (2.f * mu12 + C1c) * (2.f * sxy + C2c);
                    float den = (mu1s + mu2s + C1c) * (ssum + C2c);
                    ssim_sum += num * __builtin_amdgcn_rcpf(den);
                }
            }
        }
    }

    // ---- Block reduction, then hashed double atomics
    #pragma unroll
    for (int off = 32; off > 0; off >>= 1) {
        ssim_sum += __shfl_down(ssim_sum, off);
        l1_sum   += __shfl_down(l1_sum, off);
    }
    if ((tid & 63) == 0) { red[wid] = ssim_sum; red[4 + wid] = l1_sum; }
    __syncthreads();
    if (tid == 0) {
        float s = red[0] + red[1] + red[2] + red[3];
        float l = red[4] + red[5] + red[6] + red[7];
        double* slot = accum + (size_t)(orig & (NSLOT - 1)) * 2;
        atomicAdd(&slot[0], (double)l);
        atomicAdd(&slot[1], (double)s);
    }
}

__global__ __launch_bounds__(NSLOT) void photo_final(
    const double* __restrict__ accum, float* __restrict__ out, double invN)
{
    __shared__ double sl[8], ss[8];
    int tid = threadIdx.x;
    double l = accum[tid * 2 + 0];
    double s = accum[tid * 2 + 1];
    #pragma unroll
    for (int off = 32; off > 0; off >>= 1) {
        l += __shfl_down(l, off);
        s += __shfl_down(s, off);
    }
    if ((tid & 63) == 0) { sl[tid >> 6] = l; ss[tid >> 6] = s; }
    __syncthreads();
    if (tid == 0) {
        double L = 0.0, S = 0.0;
        #pragma unroll
        for (int i = 0; i < NSLOT / 64; ++i) { L += sl[i]; S += ss[i]; }
        double l1    = L * invN;
        double ssim  = S * invN;
        double dssim = (1.0 - ssim) * 0.5;
        out[0] = (float)(0.8 * l1 + 0.2 * dssim);
        out[1] = (float)l1;
        out[2] = (float)dssim;
    }
}

extern "C" void kernel_launch(void* const* d_in, const int* in_sizes, int n_in,
                              void* d_out, int out_size, void* d_ws, size_t ws_size,
                              hipStream_t stream)
{
    const int H = 1080, W = 1920, C = 3;
    const float* x = (const float*)d_in[0];
    const float* y = (const float*)d_in[1];
    int B = in_sizes[0] / (H * W * C);

    double* accum = (double*)d_ws;
    (void)hipMemsetAsync(d_ws, 0, NSLOT * 2 * sizeof(double), stream);

    dim3 grid(GX, GY, B);
    int nwg = GX * GY * B;
    photo_main<<<grid, dim3(256), 0, stream>>>(x, y, accum, B, nwg);

    double invN = 1.0 / ((double)B * H * W * C);
    photo_final<<<1, NSLOT, 0, stream>>>(accum, (float*)d_out, invN);
}

// Round 16
// 58.068 us; speedup vs baseline: 1.5702x; 1.0098x over previous
//
#include <hip/hip_runtime.h>
#include <hip/hip_fp16.h>

// PhotometricLoss: total = 0.8*L1 + 0.2*DSSIM; fused separable 11x11 Gaussian
// SSIM, SAME zero padding. Inputs BHWC fp32 (B=4,H=1080,W=1920,C=3).
// R16 (= R15 + LDS diet): SPAIR 26 -> 22. The h-pass k2=2 tail columns are
// STRUCTURALLY zero-weighted (g-index >= 11 for k_local >= 10, every lane),
// so out-of-row halves need only be FINITE: pairs 22,23 alias the next row's
// real data; only pair 21/row + 2 slack words past channel 2 are zeroed
// (uninitialized LDS could encode NaN; NaN*0 = NaN in MFMA).
// LDS 26.2 -> 21.7 KB -> 7 blocks/CU (28 waves). Zero-fill phase deleted.

typedef __fp16 hf4 __attribute__((ext_vector_type(4)));
typedef float f32x4 __attribute__((ext_vector_type(4)));

#define TW 32
#define TH 32
#define IH 42         // staged real rows
#define NPAIR 21      // data col-pairs per row
#define SPAIR 22      // row stride in uint2 (176 B; 12-bank rotation, ~2-way)
#define CHS (IH * SPAIR)   // uint2 per channel plane (924)
#define NSLOT 512
#define HH 1080
#define WW 1920
#define GX 60
#define GY 34

// Gaussian(sigma=1.5, 11 taps), normalized; matches fp32 reference within ~2e-7
static constexpr float G[11] = {
    0.00102838f, 0.00759876f, 0.03600077f, 0.10936069f, 0.21300554f,
    0.26601174f, 0.21300554f, 0.10936069f, 0.03600077f, 0.00759876f,
    0.00102838f};

// ---- constexpr f32 -> f16 bits (RNE); G values are all f16-normal
constexpr unsigned short f2h_cx(float f) {
    unsigned u = __builtin_bit_cast(unsigned, f);
    if ((u & 0x7fffffffu) == 0) return 0;
    int e = (int)((u >> 23) & 0xff) - 127 + 15;
    unsigned man = u & 0x7fffffu;
    unsigned m = man >> 13;
    unsigned rest = man & 0x1fffu;
    if (rest > 0x1000u || (rest == 0x1000u && (m & 1u))) {
        if (++m == 0x400u) { m = 0; ++e; }
    }
    return (unsigned short)((e << 10) | m);
}
constexpr float Gf(int d) { return (d >= 0 && d <= 10) ? G[d] : 0.0f; }
constexpr unsigned wpk(int d) {
    return (unsigned)f2h_cx(Gf(d)) | ((unsigned)f2h_cx(Gf(d + 1)) << 16);
}
// Band fragment tables (the only two nonzero tile-deltas):
// idx 0: halves g[lk - lr + i]; idx 1: g[16 + lk - lr + i].
struct WTbl {
    unsigned long long v[2][64];
    constexpr WTbl() : v{} {
        for (int dl = 0; dl < 2; ++dl)
            for (int l = 0; l < 64; ++l) {
                int d0 = 16 * dl + ((l >> 4) << 2) - (l & 15);
                v[dl][l] = (unsigned long long)wpk(d0) |
                           ((unsigned long long)wpk(d0 + 2) << 32);
            }
    }
};
__device__ const WTbl WT{};

struct f4u { float x, y, z, w; } __attribute__((packed, aligned(4)));

__device__ __forceinline__ unsigned int pkrtz(float a, float b) {
    return __builtin_bit_cast(unsigned int, __builtin_amdgcn_cvt_pkrtz(a, b));
}
__device__ __forceinline__ hf4 pk4(const f32x4& d) {
    uint2 u = make_uint2(pkrtz(d[0], d[1]), pkrtz(d[2], d[3]));
    return __builtin_bit_cast(hf4, u);
}
__device__ __forceinline__ f32x4 mfma16(hf4 a, hf4 b, f32x4 c) {
#if defined(__HIP_DEVICE_COMPILE__)
    return __builtin_amdgcn_mfma_f32_16x16x16f16(a, b, c, 0, 0, 0);
#else
    (void)a; (void)b;
    return c;   // host pass: never executed, just needs to parse
#endif
}

__global__ __launch_bounds__(256, 7) void photo_main(
    const float* __restrict__ xin, const float* __restrict__ yin,
    double* __restrict__ accum, int B, int nwg)
{
    __shared__ __align__(16) uint2 sXY[3 * CHS + 2];  // 22192 B, channel-outer
    __shared__ float red[8];

    // ---- bijective XCD swizzle (nwg % 8 == 0)
    int orig = blockIdx.x + GX * (blockIdx.y + GY * blockIdx.z);
    int nid = ((nwg & 7) == 0) ? ((orig & 7) * (nwg >> 3) + (orig >> 3)) : orig;
    int tx   = nid % GX;
    int rest = nid / GX;
    int by   = rest % GY;
    int b    = rest / GY;
    const int row0 = by * TH, col0 = tx * TW;
    const int tid  = threadIdx.x;
    const int lane = tid & 63;
    const int wid  = tid >> 6;
    const int imgbase = b * (HH * WW * 3);

    // ---- finite-fill: pair 21 of every (ch, row) + 2 slack words past ch2.
    // These are read by the h-pass k2=2 tail with structurally-zero weights;
    // they must be finite (not necessarily zero) to avoid NaN*0 in MFMA.
    if (tid < 126) {
        int ch = tid / IH, r = tid - ch * IH;
        sXY[ch * CHS + r * SPAIR + NPAIR] = make_uint2(0u, 0u);
    } else if (tid < 128) {
        sXY[3 * CHS + (tid - 126)] = make_uint2(0u, 0u);
    }

    // ---- Phase 1a: stage all 3 channels as interleaved (x,y) f16 pairs;
    // fold L1 (all channels) over the central 32x32.
    float l1_sum = 0.f;
    const bool interior = (tx >= 1) && (tx <= 58) && (by >= 1) && (by <= 32);
    if (interior) {
        for (int i = tid; i < IH * NPAIR; i += 256) {
            int r  = i / NPAIR;
            int pc = i - r * NPAIR;
            int gr  = row0 - 5 + r;
            int gc0 = col0 - 5 + 2 * pc;
            int base = imgbase + (gr * WW + gc0) * 3;
            f4u vx0 = *(const f4u*)&xin[base];        // x0c0 x0c1 x0c2 x1c0
            f4u vx1 = *(const f4u*)&xin[base + 2];    // x0c2 x1c0 x1c1 x1c2
            f4u vy0 = *(const f4u*)&yin[base];
            f4u vy1 = *(const f4u*)&yin[base + 2];
            float x0[3] = {vx0.x, vx0.y, vx0.z};
            float x1[3] = {vx1.y, vx1.z, vx1.w};
            float y0[3] = {vy0.x, vy0.y, vy0.z};
            float y1[3] = {vy1.y, vy1.z, vy1.w};
            #pragma unroll
            for (int c = 0; c < 3; ++c)
                sXY[c * CHS + r * SPAIR + pc] =
                    make_uint2(pkrtz(x0[c], x1[c]), pkrtz(y0[c], y1[c]));
            if (r >= 5 && r < 5 + TH) {
                if (pc >= 3 && pc <= 18)
                    l1_sum += fabsf(x0[0] - y0[0]) + fabsf(x0[1] - y0[1]) +
                              fabsf(x0[2] - y0[2]);
                if (pc >= 2 && pc <= 17)
                    l1_sum += fabsf(x1[0] - y1[0]) + fabsf(x1[1] - y1[1]) +
                              fabsf(x1[2] - y1[2]);
            }
        }
    } else {
        #pragma unroll 1
        for (int i = tid; i < IH * NPAIR; i += 256) {
            int r  = i / NPAIR;
            int pc = i - r * NPAIR;
            int gr  = row0 - 5 + r;
            int gc0 = col0 - 5 + 2 * pc;
            bool rin = (unsigned)gr < (unsigned)HH;
            bool c0  = rin && ((unsigned)gc0       < (unsigned)WW);
            bool c1  = rin && ((unsigned)(gc0 + 1) < (unsigned)WW);
            int base = imgbase + (gr * WW + gc0) * 3;
            float x0[3] = {0.f, 0.f, 0.f}, x1[3] = {0.f, 0.f, 0.f};
            float y0[3] = {0.f, 0.f, 0.f}, y1[3] = {0.f, 0.f, 0.f};
            #pragma unroll
            for (int c = 0; c < 3; ++c) {
                if (c0) { x0[c] = xin[base + c];     y0[c] = yin[base + c]; }
                if (c1) { x1[c] = xin[base + 3 + c]; y1[c] = yin[base + 3 + c]; }
            }
            #pragma unroll
            for (int c = 0; c < 3; ++c)
                sXY[c * CHS + r * SPAIR + pc] =
                    make_uint2(pkrtz(x0[c], x1[c]), pkrtz(y0[c], y1[c]));
            if (r >= 5 && r < 5 + TH) {
                if (c0 && pc >= 3 && pc <= 18)
                    l1_sum += fabsf(x0[0] - y0[0]) + fabsf(x0[1] - y0[1]) +
                              fabsf(x0[2] - y0[2]);
                if (c1 && pc >= 2 && pc <= 17)
                    l1_sum += fabsf(x1[0] - y1[0]) + fabsf(x1[1] - y1[1]) +
                              fabsf(x1[2] - y1[2]);
            }
        }
    }
    __syncthreads();

    // ---- quadrant-per-wave conv: wave wid -> out quadrant (u,n), 16x16,
    // all 4 moment planes; register-chained h->v; SSIM from registers.
    const int lr = lane & 15;
    const int lk = (lane >> 4) << 2;
    const int u = wid >> 1, n = wid & 1;
    hf4 wfA = __builtin_bit_cast(hf4, WT.v[0][lane]);
    hf4 wfB = __builtin_bit_cast(hf4, WT.v[1][lane]);

    // clamped read rows: rows >= 42 (only t=2, lr >= 10) fold to row 41;
    // the garbage HC rows 42..47 carry structurally-zero v-pass weights.
    int rrow[2];
    #pragma unroll
    for (int dt = 0; dt < 2; ++dt)
        rrow[dt] = min(16 * (u + dt) + lr, IH - 1) * SPAIR;

    const float C1c = 1e-4f, C2c = 9e-4f;
    float ssim_sum = 0.f;
    const bool fullq = (row0 + 16 * u + 15) < HH;   // whole quadrant in-image
    #pragma unroll 1
    for (int ch = 0; ch < 3; ++ch) {
        const uint2* S = sXY + ch * CHS;
        // read the 4 staged b128 fragments (t = u+dt, k2 = n+dk)
        uint4 rd[2][2];
        #pragma unroll
        for (int dt = 0; dt < 2; ++dt)
            #pragma unroll
            for (int dk = 0; dk < 2; ++dk)
                rd[dt][dk] = *(const uint4*)
                    &S[rrow[dt] + 8 * (n + dk) + (lk >> 1)];
        // h-pass: HC tiles t=u,u+1 for col-block n, 4 planes
        hf4 bfr[4][2];
        #pragma unroll
        for (int dt = 0; dt < 2; ++dt) {
            f32x4 d[4];
            #pragma unroll
            for (int p = 0; p < 4; ++p) d[p] = (f32x4){0.f, 0.f, 0.f, 0.f};
            #pragma unroll
            for (int dk = 0; dk < 2; ++dk) {
                uint4 v = rd[dt][dk];
                hf4 xv = __builtin_bit_cast(hf4, make_uint2(v.x, v.z));
                hf4 yv = __builtin_bit_cast(hf4, make_uint2(v.y, v.w));
                hf4 zv = xv * xv + yv * yv;
                hf4 wv = xv * yv;
                hf4 wB = dk ? wfB : wfA;
                d[0] = mfma16(xv, wB, d[0]);
                d[1] = mfma16(yv, wB, d[1]);
                d[2] = mfma16(zv, wB, d[2]);
                d[3] = mfma16(wv, wB, d[3]);
            }
            #pragma unroll
            for (int p = 0; p < 4; ++p) bfr[p][dt] = pk4(d[p]);
        }
        // v-pass: OUT quadrant = Wv x HC
        f32x4 vacc[4];
        #pragma unroll
        for (int p = 0; p < 4; ++p) {
            vacc[p] = (f32x4){0.f, 0.f, 0.f, 0.f};
            vacc[p] = mfma16(wfA, bfr[p][0], vacc[p]);
            vacc[p] = mfma16(wfB, bfr[p][1], vacc[p]);
        }
        // SSIM directly from registers
        if (fullq) {
            #pragma unroll
            for (int g2 = 0; g2 < 4; ++g2) {
                float mu1 = vacc[0][g2], mu2 = vacc[1][g2];
                float s2s = vacc[2][g2], s12 = vacc[3][g2];
                float mu1s = mu1 * mu1, mu2s = mu2 * mu2, mu12 = mu1 * mu2;
                float ssum = s2s - mu1s - mu2s;
                float sxy  = s12 - mu12;
                float num = (2.f * mu12 + C1c) * (2.f * sxy + C2c);
                float den = (mu1s + mu2s + C1c) * (ssum + C2c);
                ssim_sum += num * __builtin_amdgcn_rcpf(den);
            }
        } else {
            #pragma unroll
            for (int g2 = 0; g2 < 4; ++g2) {
                int gr = row0 + 16 * u + lk + g2;
                if (gr < HH) {
                    float mu1 = vacc[0][g2], mu2 = vacc[1][g2];
                    float s2s = vacc[2][g2], s12 = vacc[3][g2];
                    float mu1s = mu1 * mu1, mu2s = mu2 * mu2, mu12 = mu1 * mu2;
                    float ssum = s2s - mu1s - mu2s;
                    float sxy  = s12 - mu12;
                    float num = (2.f * mu12 + C1c) * (2.f * sxy + C2c);
                    float den = (mu1s + mu2s + C1c) * (ssum + C2c);
                    ssim_sum += num * __builtin_amdgcn_rcpf(den);
                }
            }
        }
    }

    // ---- Block reduction, then hashed double atomics
    #pragma unroll
    for (int off = 32; off > 0; off >>= 1) {
        ssim_sum += __shfl_down(ssim_sum, off);
        l1_sum   += __shfl_down(l1_sum, off);
    }
    if ((tid & 63) == 0) { red[wid] = ssim_sum; red[4 + wid] = l1_sum; }
    __syncthreads();
    if (tid == 0) {
        float s = red[0] + red[1] + red[2] + red[3];
        float l = red[4] + red[5] + red[6] + red[7];
        double* slot = accum + (size_t)(orig & (NSLOT - 1)) * 2;
        atomicAdd(&slot[0], (double)l);
        atomicAdd(&slot[1], (double)s);
    }
}

__global__ __launch_bounds__(NSLOT) void photo_final(
    const double* __restrict__ accum, float* __restrict__ out, double invN)
{
    __shared__ double sl[8], ss[8];
    int tid = threadIdx.x;
    double l = accum[tid * 2 + 0];
    double s = accum[tid * 2 + 1];
    #pragma unroll
    for (int off = 32; off > 0; off >>= 1) {
        l += __shfl_down(l, off);
        s += __shfl_down(s, off);
    }
    if ((tid & 63) == 0) { sl[tid >> 6] = l; ss[tid >> 6] = s; }
    __syncthreads();
    if (tid == 0) {
        double L = 0.0, S = 0.0;
        #pragma unroll
        for (int i = 0; i < NSLOT / 64; ++i) { L += sl[i]; S += ss[i]; }
        double l1    = L * invN;
        double ssim  = S * invN;
        double dssim = (1.0 - ssim) * 0.5;
        out[0] = (float)(0.8 * l1 + 0.2 * dssim);
        out[1] = (float)l1;
        out[2] = (float)dssim;
    }
}

extern "C" void kernel_launch(void* const* d_in, const int* in_sizes, int n_in,
                              void* d_out, int out_size, void* d_ws, size_t ws_size,
                              hipStream_t stream)
{
    const int H = 1080, W = 1920, C = 3;
    const float* x = (const float*)d_in[0];
    const float* y = (const float*)d_in[1];
    int B = in_sizes[0] / (H * W * C);

    double* accum = (double*)d_ws;
    (void)hipMemsetAsync(d_ws, 0, NSLOT * 2 * sizeof(double), stream);

    dim3 grid(GX, GY, B);
    int nwg = GX * GY * B;
    photo_main<<<grid, dim3(256), 0, stream>>>(x, y, accum, B, nwg);

    double invN = 1.0 / ((double)B * H * W * C);
    photo_final<<<1, NSLOT, 0, stream>>>(accum, (float*)d_out, invN);
}